// Round 7
// baseline (161.749 us; speedup 1.0000x reference)
//
#include <hip/hip_runtime.h>
#include <cstdint>

typedef __attribute__((ext_vector_type(8))) short short8;
typedef __attribute__((ext_vector_type(4))) float f32x4;

static __device__ __forceinline__ unsigned short f2bf(float x) {
  union { float f; unsigned int u; } c; c.f = x;
  unsigned int u = c.u;
  unsigned int r = (u + 0x7fffu + ((u >> 16) & 1u)) >> 16;  // RNE
  return (unsigned short)r;
}

static __device__ __forceinline__ void gl_lds16(const void* g, void* l) {
  __builtin_amdgcn_global_load_lds((const __attribute__((address_space(1))) void*)g,
                                   (__attribute__((address_space(3))) void*)l, 16, 0, 0);
}

// ---------- fp32 -> bf16 elementwise (vectorized x4) ----------
__global__ __launch_bounds__(256) void k_f32_to_bf16(const float* __restrict__ src,
                                                     unsigned short* __restrict__ dst,
                                                     int n4) {
  int i = blockIdx.x * 256 + threadIdx.x;
  if (i >= n4) return;
  float4 v = reinterpret_cast<const float4*>(src)[i];
  ushort4 o;
  o.x = f2bf(v.x); o.y = f2bf(v.y); o.z = f2bf(v.z); o.w = f2bf(v.w);
  reinterpret_cast<ushort4*>(dst)[i] = o;
}

// ---------- fused transpose of all 4 weights (demux by block id) ----------
__global__ __launch_bounds__(256) void k_transpose_all(const float* __restrict__ wq,
                                                       const float* __restrict__ wk,
                                                       const float* __restrict__ wv,
                                                       const float* __restrict__ wo,
                                                       unsigned short* __restrict__ wqt,
                                                       unsigned short* __restrict__ wkt,
                                                       unsigned short* __restrict__ wvt,
                                                       unsigned short* __restrict__ wot) {
  __shared__ float tile[32][33];
  int id = blockIdx.x;
  const float* src; unsigned short* dst; int N, t;
  if (id < 4096)       { src = wq; dst = wqt; N = 2048; t = id; }
  else if (id < 8192)  { src = wo; dst = wot; N = 2048; t = id - 4096; }
  else if (id < 9216)  { src = wk; dst = wkt; N = 512;  t = id - 8192; }
  else                 { src = wv; dst = wvt; N = 512;  t = id - 9216; }
  const int K = 2048;
  int ntx = N >> 5;
  int bn = (t % ntx) * 32, bk = (t / ntx) * 32;
  int tx = threadIdx.x & 31, ty = threadIdx.x >> 5;
#pragma unroll
  for (int i = 0; i < 32; i += 8)
    tile[ty + i][tx] = src[(size_t)(bk + ty + i) * N + bn + tx];
  __syncthreads();
#pragma unroll
  for (int i = 0; i < 32; i += 8)
    dst[(size_t)(bn + ty + i) * K + bk + tx] = f2bf(tile[tx][ty + i]);
}

// ---------- fused RoPE (Q + K) fp32 -> bf16; Q pre-scaled by 1/sqrt(128)*log2(e) ----------
__global__ __launch_bounds__(256) void k_rope_fused(const float* __restrict__ qkvf,
                                                    unsigned short* __restrict__ qd,
                                                    unsigned short* __restrict__ kd) {
  int idx = blockIdx.x * 256 + threadIdx.x;   // 2048*20*64 total
  int i = idx & 63;
  int hh = (idx >> 6) % 20;
  int s = idx / (64 * 20);
  float freq = powf(10000.0f, -(float)i / 64.0f);
  float ang = (float)s * freq;
  float sn, cs;
  sincosf(ang, &sn, &cs);
  size_t sb; unsigned short* dp; float amp;
  if (hh < 16) {
    int col = hh * 128 + 2 * i;
    sb = (size_t)s * 3072 + col;
    dp = qd + (size_t)s * 2048 + col;
    amp = 0.12751742836257666f;   // scale * log2(e): softmax in exp2 domain
  } else {
    int col = (hh - 16) * 128 + 2 * i;
    sb = (size_t)s * 3072 + 2048 + col;
    dp = kd + (size_t)s * 512 + col;
    amp = 1.0f;
  }
  float re = qkvf[sb] * amp, im = qkvf[sb + 1] * amp;
  unsigned int lo = f2bf(re * cs - im * sn);
  unsigned int hi = f2bf(re * sn + im * cs);
  *(unsigned int*)dp = lo | (hi << 16);
}

// ---------- bf16 MFMA GEMM: C(MxN,f32) = A(MxK,bf16) * Bt(NxK,bf16)^T ----------
// 128x128 tile, BK=64, 256 threads = 4 waves (2x2, each 64x64). Counted-vmcnt
// pipeline: raw s_barrier, vmcnt(8) steady state (2 tiles of loads in flight),
// global_load_lds w16, 8-slot XOR swizzle both sides, bijective XCD remap.
// Epilogue: cols >= vcol0 are written bf16 TRANSPOSED to VT (d-major), else f32 to C.
__global__ __launch_bounds__(256) void k_gemm_bf16(const unsigned short* __restrict__ A,
                                                   const unsigned short* __restrict__ Bt,
                                                   float* __restrict__ C,
                                                   unsigned short* __restrict__ VT,
                                                   int M, int N, int K, int vcol0) {
  __shared__ short sA[2][128 * 64];
  __shared__ short sB[2][128 * 64];
  int tid = threadIdx.x;
  int lane = tid & 63, wid = tid >> 6;
  int wr = wid >> 1, wc = wid & 1;

  int gx = gridDim.x, nwg = gx * gridDim.y;
  int flat = blockIdx.y * gx + blockIdx.x;
  int l = (flat & 7) * (nwg >> 3) + (flat >> 3);
  int bx = l % gx, by = l / gx;
  int m0 = by * 128, n0 = bx * 128;

  f32x4 acc[4][4] = {};

  // staging: round i, thread tid -> row i*32 + (tid>>3), phys 16B slot tid&7.
  // phys slot p at row r holds logical slot p ^ (r&7); r&7 == (tid>>3)&7.
  int srcCol = (((tid & 7) ^ ((tid >> 3) & 7)) << 3);
  int rA = tid >> 3;
  const unsigned short* Ag = A + (size_t)(m0 + rA) * K + srcCol;
  const unsigned short* Bg = Bt + (size_t)(n0 + rA) * K + srcCol;
  int wb = (tid & ~63) * 8;            // wave-uniform LDS base (shorts)

  int g = lane >> 4, fr = lane & 15, sw = fr & 7;

#define STAGE_G(buf, kof) do { \
    gl_lds16(Ag + (kof),                    &sA[buf][wb]); \
    gl_lds16(Ag + 32 * (size_t)K + (kof),   &sA[buf][2048 + wb]); \
    gl_lds16(Ag + 64 * (size_t)K + (kof),   &sA[buf][4096 + wb]); \
    gl_lds16(Ag + 96 * (size_t)K + (kof),   &sA[buf][6144 + wb]); \
    gl_lds16(Bg + (kof),                    &sB[buf][wb]); \
    gl_lds16(Bg + 32 * (size_t)K + (kof),   &sB[buf][2048 + wb]); \
    gl_lds16(Bg + 64 * (size_t)K + (kof),   &sB[buf][4096 + wb]); \
    gl_lds16(Bg + 96 * (size_t)K + (kof),   &sB[buf][6144 + wb]); \
  } while (0)

  int nt = K >> 6;                     // 32
  STAGE_G(0, 0);
  STAGE_G(1, 64);

  for (int t = 0; t < nt; t++) {
    if (t < nt - 1) {
      asm volatile("s_waitcnt vmcnt(8)" ::: "memory");   // tile t landed; t+1 in flight
    } else {
      asm volatile("s_waitcnt vmcnt(0)" ::: "memory");
    }
    __builtin_amdgcn_sched_barrier(0);
    __builtin_amdgcn_s_barrier();      // buf[t&1] complete for all waves

    const short* sAc = sA[t & 1];
    const short* sBc = sB[t & 1];
#pragma unroll
    for (int kk = 0; kk < 2; kk++) {
      int so = ((((kk << 2) + g) ^ sw) << 3);
      short8 af[4], bf4[4];
#pragma unroll
      for (int x = 0; x < 4; x++)
        af[x] = *(const short8*)(sAc + (wr * 64 + x * 16 + fr) * 64 + so);
#pragma unroll
      for (int ni = 0; ni < 4; ni++)
        bf4[ni] = *(const short8*)(sBc + (wc * 64 + ni * 16 + fr) * 64 + so);
#pragma unroll
      for (int x = 0; x < 4; x++)
#pragma unroll
        for (int ni = 0; ni < 4; ni++)
          acc[x][ni] = __builtin_amdgcn_mfma_f32_16x16x32_bf16(af[x], bf4[ni], acc[x][ni], 0, 0, 0);
    }

    __builtin_amdgcn_s_barrier();      // all waves done reading buf[t&1]
    if (t + 2 < nt) STAGE_G(t & 1, (size_t)((t + 2) << 6));
  }
#undef STAGE_G

  int rb = m0 + wr * 64 + (g << 2);
#pragma unroll
  for (int ni = 0; ni < 4; ni++) {
    int col = n0 + wc * 64 + ni * 16 + fr;
    if (col >= vcol0) {
      // V region: write bf16 transposed, VT[(col-vcol0)][row], rows contiguous
#pragma unroll
      for (int x = 0; x < 4; x++) {
        ushort4 pk;
        pk.x = f2bf(acc[x][ni][0]); pk.y = f2bf(acc[x][ni][1]);
        pk.z = f2bf(acc[x][ni][2]); pk.w = f2bf(acc[x][ni][3]);
        *(ushort4*)(VT + (size_t)(col - vcol0) * 2048 + rb + x * 16) = pk;
      }
    } else {
#pragma unroll
      for (int x = 0; x < 4; x++)
#pragma unroll
        for (int j = 0; j < 4; j++)
          C[(size_t)(rb + x * 16 + j) * N + col] = acc[x][ni][j];
    }
  }
}

// ---------- bf16 MFMA flash attention, GQA, causal ----------
// (unchanged from R6: swapped QK^T, defer-max, dbuf K/V, reg prefetch, setprio)
#define KSTR 136
#define VSTR 72
#define PSTR 72
__global__ __launch_bounds__(256) void k_attn_mfma(const unsigned short* __restrict__ Qb,
                                                   const unsigned short* __restrict__ Kb,
                                                   const unsigned short* __restrict__ Vt,
                                                   unsigned short* __restrict__ O) {
  __shared__ short sK[2][64 * KSTR];
  __shared__ short sV[2][128 * VSTR];
  __shared__ short sP[4][16 * PSTR];
  int h = blockIdx.y;
  int x = blockIdx.x;
  int qb = (h < 8) ? x : (31 - x);
  int q0 = qb * 64;
  int kvh = h >> 2;
  int tid = threadIdx.x, lane = tid & 63, w = tid >> 6;
  int fr = lane & 15, g = lane >> 4, kq = g << 3;

  short8 qf[4];
  {
    const unsigned short* qrow = Qb + (size_t)(q0 + w * 16 + fr) * 2048 + h * 128 + kq;
#pragma unroll
    for (int ko = 0; ko < 4; ko++) qf[ko] = *(const short8*)(qrow + ko * 32);
  }

  f32x4 oacc[8];
#pragma unroll
  for (int nd = 0; nd < 8; nd++) oacc[nd] = (f32x4){0.f, 0.f, 0.f, 0.f};
  float m_i = -3e38f;
  float l_i = 0.f;

  int skr = tid >> 2, skc = (tid & 3) << 5;
  int svd = tid >> 1, svc = (tid & 1) << 5;
  const unsigned short* Kbase = Kb + (size_t)kvh * 128 + skc;
  const unsigned short* Vbase = Vt + (size_t)(kvh * 128 + svd) * 2048 + svc;
  short* pw = (short*)sP[w];
  int kdOff = skr * KSTR + skc;
  int vdOff = svd * VSTR + svc;

  short8 kreg[4], vreg[4];
  {
    const short8* ks = (const short8*)(Kbase + (size_t)skr * 512);
    const short8* vs = (const short8*)(Vbase);
#pragma unroll
    for (int j = 0; j < 4; j++) { kreg[j] = ks[j]; vreg[j] = vs[j]; }
  }
  {
    short* kd = sK[0] + kdOff; short* vd = sV[0] + vdOff;
#pragma unroll
    for (int j = 0; j < 4; j++) { *(short8*)(kd + j * 8) = kreg[j]; *(short8*)(vd + j * 8) = vreg[j]; }
  }
  if (qb >= 1) {
    const short8* ks = (const short8*)(Kbase + (size_t)(64 + skr) * 512);
    const short8* vs = (const short8*)(Vbase + 64);
#pragma unroll
    for (int j = 0; j < 4; j++) { kreg[j] = ks[j]; vreg[j] = vs[j]; }
  }
  __syncthreads();

  int qrowS = q0 + w * 16 + fr;

  for (int kt = 0; kt <= qb; kt++) {
    int c = kt & 1;
    const short* sKc = sK[c];
    const short* sVc = sV[c];

    // S^T = K Q^T : lane (fr,g), reg (ni,j) = S[q=fr][kcol = ni*16 + g*4 + j]
    f32x4 sacc[4];
#pragma unroll
    for (int ni = 0; ni < 4; ni++) sacc[ni] = (f32x4){0.f, 0.f, 0.f, 0.f};
    __builtin_amdgcn_s_setprio(1);
#pragma unroll
    for (int ko = 0; ko < 4; ko++)
#pragma unroll
      for (int ni = 0; ni < 4; ni++) {
        short8 kf = *(const short8*)(sKc + (ni * 16 + fr) * KSTR + kq + ko * 32);
        sacc[ni] = __builtin_amdgcn_mfma_f32_16x16x32_bf16(kf, qf[ko], sacc[ni], 0, 0, 0);
      }
    __builtin_amdgcn_s_setprio(0);

    if (kt == qb) {
      int k0 = kt * 64;
#pragma unroll
      for (int ni = 0; ni < 4; ni++) {
        int kc = k0 + ni * 16 + (g << 2);
#pragma unroll
        for (int j = 0; j < 4; j++)
          if (kc + j > qrowS) sacc[ni][j] = -3e38f;
      }
    }

    float tm = sacc[0][0];
#pragma unroll
    for (int ni = 0; ni < 4; ni++)
#pragma unroll
      for (int j = 0; j < 4; j++) tm = fmaxf(tm, sacc[ni][j]);
    tm = fmaxf(tm, __shfl_xor(tm, 16));
    tm = fmaxf(tm, __shfl_xor(tm, 32));

    if (!__all(tm <= m_i + 8.0f)) {
      float mn = fmaxf(m_i, tm);
      float sc = exp2f(m_i - mn);
      m_i = mn;
      float scj[4];
#pragma unroll
      for (int j = 0; j < 4; j++) scj[j] = __shfl(sc, (g << 2) + j);
#pragma unroll
      for (int nd = 0; nd < 8; nd++)
#pragma unroll
        for (int j = 0; j < 4; j++) oacc[nd][j] *= scj[j];
      l_i *= sc;
    }

    float ps = 0.f;
#pragma unroll
    for (int ni = 0; ni < 4; ni++) {
      float p0 = exp2f(sacc[ni][0] - m_i);
      float p1 = exp2f(sacc[ni][1] - m_i);
      float p2 = exp2f(sacc[ni][2] - m_i);
      float p3 = exp2f(sacc[ni][3] - m_i);
      ps += (p0 + p1) + (p2 + p3);
      ushort4 pk;
      pk.x = f2bf(p0); pk.y = f2bf(p1); pk.z = f2bf(p2); pk.w = f2bf(p3);
      *(ushort4*)(pw + fr * PSTR + ni * 16 + (g << 2)) = pk;
    }
    ps += __shfl_xor(ps, 16);
    ps += __shfl_xor(ps, 32);
    l_i += ps;

    __builtin_amdgcn_s_setprio(1);
#pragma unroll
    for (int ks = 0; ks < 2; ks++) {
      short8 pa = *(const short8*)(pw + fr * PSTR + kq + ks * 32);
#pragma unroll
      for (int nd = 0; nd < 8; nd++) {
        short8 vb = *(const short8*)(sVc + (nd * 16 + fr) * VSTR + kq + ks * 32);
        oacc[nd] = __builtin_amdgcn_mfma_f32_16x16x32_bf16(pa, vb, oacc[nd], 0, 0, 0);
      }
    }
    __builtin_amdgcn_s_setprio(0);

    if (kt < qb) {
      short* kd = sK[c ^ 1] + kdOff; short* vd = sV[c ^ 1] + vdOff;
#pragma unroll
      for (int j = 0; j < 4; j++) { *(short8*)(kd + j * 8) = kreg[j]; *(short8*)(vd + j * 8) = vreg[j]; }
      if (kt + 1 < qb) {
        int k2 = (kt + 2) * 64;
        const short8* ks = (const short8*)(Kbase + (size_t)(k2 + skr) * 512);
        const short8* vs = (const short8*)(Vbase + k2);
#pragma unroll
        for (int j = 0; j < 4; j++) { kreg[j] = ks[j]; vreg[j] = vs[j]; }
      }
      __syncthreads();
    }
  }

  int orow = q0 + w * 16 + (g << 2);
#pragma unroll
  for (int j = 0; j < 4; j++) {
    float lj = __shfl(l_i, (g << 2) + j);
    float inv = 1.0f / lj;
#pragma unroll
    for (int nd = 0; nd < 8; nd++)
      O[(size_t)(orow + j) * 2048 + h * 128 + nd * 16 + fr] = f2bf(oacc[nd][j] * inv);
  }
}

extern "C" void kernel_launch(void* const* d_in, const int* in_sizes, int n_in,
                              void* d_out, int out_size, void* d_ws, size_t ws_size,
                              hipStream_t stream) {
  const float* hs = (const float*)d_in[0];
  const float* wq = (const float*)d_in[1];
  const float* wk = (const float*)d_in[2];
  const float* wv = (const float*)d_in[3];
  const float* wo = (const float*)d_in[4];
  char* ws = (char*)d_ws;

  unsigned short* hb   = (unsigned short*)(ws);             // 2048x2048 bf16; later ao
  unsigned short* wqt  = (unsigned short*)(ws + 8388608);   // 2048x2048 bf16; later q_bf
  unsigned short* wkt  = (unsigned short*)(ws + 16777216);  // 512x2048 bf16;  later k_bf
  unsigned short* wvt  = (unsigned short*)(ws + 18874368);  // 512x2048 bf16;  later vt_bf
  unsigned short* wot  = (unsigned short*)(ws + 20971520);  // 2048x2048 bf16
  float* qkvf          = (float*)(ws + 29360128);           // 2048x3072 f32 (V cols unused)
  unsigned short* q_bf = wqt;
  unsigned short* k_bf = wkt;
  unsigned short* vt_bf = wvt;
  unsigned short* ao   = hb;
  float* out = (float*)d_out;

  k_f32_to_bf16<<<4096, 256, 0, stream>>>(hs, hb, 2048 * 2048 / 4);
  k_transpose_all<<<10240, 256, 0, stream>>>(wq, wk, wv, wo, wqt, wkt, wvt, wot);

  // fused QKV projection; V columns (>=2560) stream out bf16-transposed to vt_bf
  k_gemm_bf16<<<dim3(24, 16), 256, 0, stream>>>(hb, wqt, qkvf, vt_bf, 2048, 3072, 2048, 2560);

  k_rope_fused<<<10240, 256, 0, stream>>>(qkvf, q_bf, k_bf);

  k_attn_mfma<<<dim3(32, 16), 256, 0, stream>>>(q_bf, k_bf, vt_bf, ao);

  // output projection (no V region)
  k_gemm_bf16<<<dim3(16, 16), 256, 0, stream>>>(ao, wot, out, (unsigned short*)nullptr,
                                                2048, 2048, 2048, 1 << 30);
}

// Round 8
// 147.046 us; speedup vs baseline: 1.1000x; 1.1000x over previous
//
#include <hip/hip_runtime.h>
#include <cstdint>

typedef __attribute__((ext_vector_type(8))) short short8;
typedef __attribute__((ext_vector_type(4))) float f32x4;

static __device__ __forceinline__ unsigned short f2bf(float x) {
  union { float f; unsigned int u; } c; c.f = x;
  unsigned int u = c.u;
  unsigned int r = (u + 0x7fffu + ((u >> 16) & 1u)) >> 16;  // RNE
  return (unsigned short)r;
}

static __device__ __forceinline__ void gl_lds16(const void* g, void* l) {
  __builtin_amdgcn_global_load_lds((const __attribute__((address_space(1))) void*)g,
                                   (__attribute__((address_space(3))) void*)l, 16, 0, 0);
}

// ---------- cos/sin table: ctab[s*64+i] = {cos(s*freq_i), sin(s*freq_i)} ----------
__global__ __launch_bounds__(256) void k_sincos(float2* __restrict__ ctab) {
  int idx = blockIdx.x * 256 + threadIdx.x;   // 2048*64
  int s = idx >> 6, i = idx & 63;
  float freq = powf(10000.0f, -(float)i / 64.0f);
  float sn, cs;
  sincosf((float)s * freq, &sn, &cs);
  ctab[idx] = make_float2(cs, sn);
}

// ---------- fp32 -> bf16 elementwise (vectorized x4) ----------
__global__ __launch_bounds__(256) void k_f32_to_bf16(const float* __restrict__ src,
                                                     unsigned short* __restrict__ dst,
                                                     int n4) {
  int i = blockIdx.x * 256 + threadIdx.x;
  if (i >= n4) return;
  float4 v = reinterpret_cast<const float4*>(src)[i];
  ushort4 o;
  o.x = f2bf(v.x); o.y = f2bf(v.y); o.z = f2bf(v.z); o.w = f2bf(v.w);
  reinterpret_cast<ushort4*>(dst)[i] = o;
}

// ---------- fused transpose of all 4 weights (demux by block id) ----------
__global__ __launch_bounds__(256) void k_transpose_all(const float* __restrict__ wq,
                                                       const float* __restrict__ wk,
                                                       const float* __restrict__ wv,
                                                       const float* __restrict__ wo,
                                                       unsigned short* __restrict__ wqt,
                                                       unsigned short* __restrict__ wkt,
                                                       unsigned short* __restrict__ wvt,
                                                       unsigned short* __restrict__ wot) {
  __shared__ float tile[32][33];
  int id = blockIdx.x;
  const float* src; unsigned short* dst; int N, t;
  if (id < 4096)       { src = wq; dst = wqt; N = 2048; t = id; }
  else if (id < 8192)  { src = wo; dst = wot; N = 2048; t = id - 4096; }
  else if (id < 9216)  { src = wk; dst = wkt; N = 512;  t = id - 8192; }
  else                 { src = wv; dst = wvt; N = 512;  t = id - 9216; }
  const int K = 2048;
  int ntx = N >> 5;
  int bn = (t % ntx) * 32, bk = (t / ntx) * 32;
  int tx = threadIdx.x & 31, ty = threadIdx.x >> 5;
#pragma unroll
  for (int i = 0; i < 32; i += 8)
    tile[ty + i][tx] = src[(size_t)(bk + ty + i) * N + bn + tx];
  __syncthreads();
#pragma unroll
  for (int i = 0; i < 32; i += 8)
    dst[(size_t)(bn + ty + i) * K + bk + tx] = f2bf(tile[tx][ty + i]);
}

// ---------- bf16 MFMA GEMM with fused epilogues ----------
// Main loop = R6 (128x64 tile, BK=64, 2-phase dbuf, global_load_lds w16,
// 8-slot XOR swizzle both sides, bijective XCD remap; one syncthreads/iter).
// Epilogue (fuse=1, QKV): col<2048 -> rope+amp -> bf16 Qd; col<2560 -> rope -> bf16 Kd;
//                         col>=2560 -> bf16 transposed to VT.
// Epilogue (fuse=0): f32 to C.
__global__ __launch_bounds__(256) void k_gemm_bf16(const unsigned short* __restrict__ A,
                                                   const unsigned short* __restrict__ Bt,
                                                   float* __restrict__ C,
                                                   unsigned short* __restrict__ Qd,
                                                   unsigned short* __restrict__ Kd,
                                                   unsigned short* __restrict__ VT,
                                                   const float2* __restrict__ ctab,
                                                   int M, int N, int K, int fuse) {
  __shared__ short sA[2][128 * 64];
  __shared__ short sB[2][64 * 64];
  int tid = threadIdx.x;
  int lane = tid & 63, wid = tid >> 6;
  int wr = wid >> 1, wc = wid & 1;

  int gx = gridDim.x, nwg = gx * gridDim.y;
  int flat = blockIdx.y * gx + blockIdx.x;
  int l = (flat & 7) * (nwg >> 3) + (flat >> 3);
  int bx = l % gx, by = l / gx;
  int m0 = by * 128, n0 = bx * 64;

  f32x4 acc[4][2] = {};

  int srcCol = (((tid & 7) ^ ((tid >> 3) & 7)) << 3);
  int rA = tid >> 3;
  const unsigned short* Ag = A + (size_t)(m0 + rA) * K + srcCol;
  const unsigned short* Bg = Bt + (size_t)(n0 + rA) * K + srcCol;
  int wb = (tid & ~63) * 8;            // wave-uniform LDS base (shorts)

  int g = lane >> 4, fr = lane & 15, sw = fr & 7;

#define STAGE_G(buf, kof) do { \
    gl_lds16(Ag + (kof),                    &sA[buf][wb]); \
    gl_lds16(Ag + 32 * (size_t)K + (kof),   &sA[buf][2048 + wb]); \
    gl_lds16(Ag + 64 * (size_t)K + (kof),   &sA[buf][4096 + wb]); \
    gl_lds16(Ag + 96 * (size_t)K + (kof),   &sA[buf][6144 + wb]); \
    gl_lds16(Bg + (kof),                    &sB[buf][wb]); \
    gl_lds16(Bg + 32 * (size_t)K + (kof),   &sB[buf][2048 + wb]); \
  } while (0)

  int nt = K >> 6;
  STAGE_G(0, 0);
  __syncthreads();

  int cur = 0;
  for (int t = 0; t < nt; t++) {
    if (t + 1 < nt) STAGE_G(cur ^ 1, (size_t)((t + 1) << 6));
    const short* sAc = sA[cur];
    const short* sBc = sB[cur];
#pragma unroll
    for (int kk = 0; kk < 2; kk++) {
      int so = ((((kk << 2) + g) ^ sw) << 3);
      short8 af[4], bf2[2];
#pragma unroll
      for (int x = 0; x < 4; x++)
        af[x] = *(const short8*)(sAc + (wr * 64 + x * 16 + fr) * 64 + so);
#pragma unroll
      for (int ni = 0; ni < 2; ni++)
        bf2[ni] = *(const short8*)(sBc + (wc * 32 + ni * 16 + fr) * 64 + so);
#pragma unroll
      for (int x = 0; x < 4; x++)
#pragma unroll
        for (int ni = 0; ni < 2; ni++)
          acc[x][ni] = __builtin_amdgcn_mfma_f32_16x16x32_bf16(af[x], bf2[ni], acc[x][ni], 0, 0, 0);
    }
    __syncthreads();
    cur ^= 1;
  }
#undef STAGE_G

  int rb = m0 + wr * 64 + (g << 2);
  if (!fuse) {
#pragma unroll
    for (int ni = 0; ni < 2; ni++) {
      int col = n0 + wc * 32 + ni * 16 + fr;
#pragma unroll
      for (int x = 0; x < 4; x++)
#pragma unroll
        for (int j = 0; j < 4; j++)
          C[(size_t)(rb + x * 16 + j) * N + col] = acc[x][ni][j];
    }
    return;
  }

  // fused QKV epilogue
  const float QAMP = 0.12751742836257666f;  // 1/sqrt(128) * log2(e)
#pragma unroll
  for (int ni = 0; ni < 2; ni++) {
    int col = n0 + wc * 32 + ni * 16 + fr;
    if (col >= 2560) {
      // V: bf16 transposed, VT[col-2560][row]
#pragma unroll
      for (int x = 0; x < 4; x++) {
        ushort4 pk;
        pk.x = f2bf(acc[x][ni][0]); pk.y = f2bf(acc[x][ni][1]);
        pk.z = f2bf(acc[x][ni][2]); pk.w = f2bf(acc[x][ni][3]);
        *(ushort4*)(VT + (size_t)(col - 2560) * 2048 + rb + x * 16) = pk;
      }
    } else {
      // rope: pair partner lives in lane fr^1 (col^1)
      int ipair = (col & 127) >> 1;
      bool even = (col & 1) == 0;
      bool isQ = col < 2048;
      unsigned short* dst = isQ ? Qd : Kd;
      int stride = isQ ? 2048 : 512;
      int dcol = isQ ? col : (col - 2048);
      float amp = isQ ? QAMP : 1.0f;
#pragma unroll
      for (int x = 0; x < 4; x++) {
        f32x4 a = acc[x][ni];
        float p0 = __shfl_xor(a[0], 1), p1 = __shfl_xor(a[1], 1);
        float p2 = __shfl_xor(a[2], 1), p3 = __shfl_xor(a[3], 1);
        float pv[4] = {p0, p1, p2, p3};
#pragma unroll
        for (int j = 0; j < 4; j++) {
          int r = rb + x * 16 + j;
          float2 cs = ctab[r * 64 + ipair];
          float o = even ? (a[j] * cs.x - pv[j] * cs.y)
                         : (pv[j] * cs.y + a[j] * cs.x);
          dst[(size_t)r * stride + dcol] = f2bf(o * amp);
        }
      }
    }
  }
}

// ---------- bf16 MFMA flash attention, GQA, causal (unchanged from R6) ----------
#define KSTR 136
#define VSTR 72
#define PSTR 72
__global__ __launch_bounds__(256) void k_attn_mfma(const unsigned short* __restrict__ Qb,
                                                   const unsigned short* __restrict__ Kb,
                                                   const unsigned short* __restrict__ Vt,
                                                   unsigned short* __restrict__ O) {
  __shared__ short sK[2][64 * KSTR];
  __shared__ short sV[2][128 * VSTR];
  __shared__ short sP[4][16 * PSTR];
  int h = blockIdx.y;
  int x = blockIdx.x;
  int qb = (h < 8) ? x : (31 - x);
  int q0 = qb * 64;
  int kvh = h >> 2;
  int tid = threadIdx.x, lane = tid & 63, w = tid >> 6;
  int fr = lane & 15, g = lane >> 4, kq = g << 3;

  short8 qf[4];
  {
    const unsigned short* qrow = Qb + (size_t)(q0 + w * 16 + fr) * 2048 + h * 128 + kq;
#pragma unroll
    for (int ko = 0; ko < 4; ko++) qf[ko] = *(const short8*)(qrow + ko * 32);
  }

  f32x4 oacc[8];
#pragma unroll
  for (int nd = 0; nd < 8; nd++) oacc[nd] = (f32x4){0.f, 0.f, 0.f, 0.f};
  float m_i = -3e38f;
  float l_i = 0.f;

  int skr = tid >> 2, skc = (tid & 3) << 5;
  int svd = tid >> 1, svc = (tid & 1) << 5;
  const unsigned short* Kbase = Kb + (size_t)kvh * 128 + skc;
  const unsigned short* Vbase = Vt + (size_t)(kvh * 128 + svd) * 2048 + svc;
  short* pw = (short*)sP[w];
  int kdOff = skr * KSTR + skc;
  int vdOff = svd * VSTR + svc;

  short8 kreg[4], vreg[4];
  {
    const short8* ks = (const short8*)(Kbase + (size_t)skr * 512);
    const short8* vs = (const short8*)(Vbase);
#pragma unroll
    for (int j = 0; j < 4; j++) { kreg[j] = ks[j]; vreg[j] = vs[j]; }
  }
  {
    short* kd = sK[0] + kdOff; short* vd = sV[0] + vdOff;
#pragma unroll
    for (int j = 0; j < 4; j++) { *(short8*)(kd + j * 8) = kreg[j]; *(short8*)(vd + j * 8) = vreg[j]; }
  }
  if (qb >= 1) {
    const short8* ks = (const short8*)(Kbase + (size_t)(64 + skr) * 512);
    const short8* vs = (const short8*)(Vbase + 64);
#pragma unroll
    for (int j = 0; j < 4; j++) { kreg[j] = ks[j]; vreg[j] = vs[j]; }
  }
  __syncthreads();

  int qrowS = q0 + w * 16 + fr;

  for (int kt = 0; kt <= qb; kt++) {
    int c = kt & 1;
    const short* sKc = sK[c];
    const short* sVc = sV[c];

    f32x4 sacc[4];
#pragma unroll
    for (int ni = 0; ni < 4; ni++) sacc[ni] = (f32x4){0.f, 0.f, 0.f, 0.f};
    __builtin_amdgcn_s_setprio(1);
#pragma unroll
    for (int ko = 0; ko < 4; ko++)
#pragma unroll
      for (int ni = 0; ni < 4; ni++) {
        short8 kf = *(const short8*)(sKc + (ni * 16 + fr) * KSTR + kq + ko * 32);
        sacc[ni] = __builtin_amdgcn_mfma_f32_16x16x32_bf16(kf, qf[ko], sacc[ni], 0, 0, 0);
      }
    __builtin_amdgcn_s_setprio(0);

    if (kt == qb) {
      int k0 = kt * 64;
#pragma unroll
      for (int ni = 0; ni < 4; ni++) {
        int kc = k0 + ni * 16 + (g << 2);
#pragma unroll
        for (int j = 0; j < 4; j++)
          if (kc + j > qrowS) sacc[ni][j] = -3e38f;
      }
    }

    float tm = sacc[0][0];
#pragma unroll
    for (int ni = 0; ni < 4; ni++)
#pragma unroll
      for (int j = 0; j < 4; j++) tm = fmaxf(tm, sacc[ni][j]);
    tm = fmaxf(tm, __shfl_xor(tm, 16));
    tm = fmaxf(tm, __shfl_xor(tm, 32));

    if (!__all(tm <= m_i + 8.0f)) {
      float mn = fmaxf(m_i, tm);
      float sc = exp2f(m_i - mn);
      m_i = mn;
      float scj[4];
#pragma unroll
      for (int j = 0; j < 4; j++) scj[j] = __shfl(sc, (g << 2) + j);
#pragma unroll
      for (int nd = 0; nd < 8; nd++)
#pragma unroll
        for (int j = 0; j < 4; j++) oacc[nd][j] *= scj[j];
      l_i *= sc;
    }

    float ps = 0.f;
#pragma unroll
    for (int ni = 0; ni < 4; ni++) {
      float p0 = exp2f(sacc[ni][0] - m_i);
      float p1 = exp2f(sacc[ni][1] - m_i);
      float p2 = exp2f(sacc[ni][2] - m_i);
      float p3 = exp2f(sacc[ni][3] - m_i);
      ps += (p0 + p1) + (p2 + p3);
      ushort4 pk;
      pk.x = f2bf(p0); pk.y = f2bf(p1); pk.z = f2bf(p2); pk.w = f2bf(p3);
      *(ushort4*)(pw + fr * PSTR + ni * 16 + (g << 2)) = pk;
    }
    ps += __shfl_xor(ps, 16);
    ps += __shfl_xor(ps, 32);
    l_i += ps;

    __builtin_amdgcn_s_setprio(1);
#pragma unroll
    for (int ks = 0; ks < 2; ks++) {
      short8 pa = *(const short8*)(pw + fr * PSTR + kq + ks * 32);
#pragma unroll
      for (int nd = 0; nd < 8; nd++) {
        short8 vb = *(const short8*)(sVc + (nd * 16 + fr) * VSTR + kq + ks * 32);
        oacc[nd] = __builtin_amdgcn_mfma_f32_16x16x32_bf16(pa, vb, oacc[nd], 0, 0, 0);
      }
    }
    __builtin_amdgcn_s_setprio(0);

    if (kt < qb) {
      short* kd = sK[c ^ 1] + kdOff; short* vd = sV[c ^ 1] + vdOff;
#pragma unroll
      for (int j = 0; j < 4; j++) { *(short8*)(kd + j * 8) = kreg[j]; *(short8*)(vd + j * 8) = vreg[j]; }
      if (kt + 1 < qb) {
        int k2 = (kt + 2) * 64;
        const short8* ks = (const short8*)(Kbase + (size_t)(k2 + skr) * 512);
        const short8* vs = (const short8*)(Vbase + k2);
#pragma unroll
        for (int j = 0; j < 4; j++) { kreg[j] = ks[j]; vreg[j] = vs[j]; }
      }
      __syncthreads();
    }
  }

  int orow = q0 + w * 16 + (g << 2);
#pragma unroll
  for (int j = 0; j < 4; j++) {
    float lj = __shfl(l_i, (g << 2) + j);
    float inv = 1.0f / lj;
#pragma unroll
    for (int nd = 0; nd < 8; nd++)
      O[(size_t)(orow + j) * 2048 + h * 128 + nd * 16 + fr] = f2bf(oacc[nd][j] * inv);
  }
}

extern "C" void kernel_launch(void* const* d_in, const int* in_sizes, int n_in,
                              void* d_out, int out_size, void* d_ws, size_t ws_size,
                              hipStream_t stream) {
  const float* hs = (const float*)d_in[0];
  const float* wq = (const float*)d_in[1];
  const float* wk = (const float*)d_in[2];
  const float* wv = (const float*)d_in[3];
  const float* wo = (const float*)d_in[4];
  char* ws = (char*)d_ws;

  unsigned short* hb   = (unsigned short*)(ws);             // 2048x2048 bf16; later ao
  unsigned short* wqt  = (unsigned short*)(ws + 8388608);   // 2048x2048 bf16
  unsigned short* wkt  = (unsigned short*)(ws + 16777216);  // 512x2048 bf16
  unsigned short* wvt  = (unsigned short*)(ws + 18874368);  // 512x2048 bf16
  unsigned short* wot  = (unsigned short*)(ws + 20971520);  // 2048x2048 bf16
  unsigned short* q_bf = (unsigned short*)(ws + 29360128);  // 2048x2048 bf16 (race-free)
  unsigned short* k_bf = (unsigned short*)(ws + 37748736);  // 2048x512 bf16
  unsigned short* vt_bf= (unsigned short*)(ws + 39845888);  // 512x2048 bf16
  float2* ctab         = (float2*)(ws + 41943040);          // 2048x64 float2 (1 MB)
  unsigned short* ao   = hb;
  float* out = (float*)d_out;

  k_sincos<<<512, 256, 0, stream>>>(ctab);
  k_f32_to_bf16<<<4096, 256, 0, stream>>>(hs, hb, 2048 * 2048 / 4);
  k_transpose_all<<<10240, 256, 0, stream>>>(wq, wk, wv, wo, wqt, wkt, wvt, wot);

  // fused QKV projection: epilogue applies rope -> q_bf/k_bf, V -> vt_bf (transposed)
  k_gemm_bf16<<<dim3(48, 16), 256, 0, stream>>>(hb, wqt, (float*)nullptr,
                                                q_bf, k_bf, vt_bf, ctab,
                                                2048, 3072, 2048, 1);

  k_attn_mfma<<<dim3(32, 16), 256, 0, stream>>>(q_bf, k_bf, vt_bf, ao);

  // output projection: plain f32 epilogue
  k_gemm_bf16<<<dim3(32, 16), 256, 0, stream>>>(ao, wot, out,
                                                (unsigned short*)nullptr,
                                                (unsigned short*)nullptr,
                                                (unsigned short*)nullptr,
                                                (const float2*)nullptr,
                                                2048, 2048, 2048, 0);
}